// Round 8
// baseline (6672.366 us; speedup 1.0000x reference)
//
#include <hip/hip_runtime.h>
#include <math.h>

// Problem dims
#define T_LEN 128
#define B_SZ  64
#define AD    32
#define ZD    64
#define KMIX  16
#define HID   128

// ---------------- workspace layout (floats) ----------------
#define WS_B0 0
#define WS_B1 512
#define WS_Q  1024
#define WS_R  5120
#define WS_W  6144     // [T][B][16] mixture weights

// ---------------- output layout (floats) ----------------
#define OUT_MEANS   0
#define OUT_COVS    524288
#define OUT_NMEANS  34078720
#define OUT_NCOVS   34603008
#define OUT_MATA    68157440
#define OUT_MATC    101711872

__device__ __forceinline__ float sigmoidf_(float x){ return 1.0f/(1.0f + expf(-x)); }

// ============ prep: biases, Q, R only (weights read directly now) ============
__global__ __launch_bounds__(256) void prep_kernel(
    const float* __restrict__ bih0, const float* __restrict__ bhh0,
    const float* __restrict__ bih1, const float* __restrict__ bhh1,
    const float* __restrict__ QL,   const float* __restrict__ RL,
    float* __restrict__ ws)
{
  int idx = blockIdx.x*256 + threadIdx.x;
  if (idx < 512) {
    ws[WS_B0 + idx] = bih0[idx] + bhh0[idx];
  } else if (idx < 1024) {
    int g = idx - 512; ws[WS_B1 + g] = bih1[g] + bhh1[g];
  } else if (idx < 5120) {              // Q = QL QL^T + 1e-3 I
    int e = idx - 1024; int i = e >> 6, j = e & 63;
    float s = (i==j) ? 1e-3f : 0.f;
    for (int k = 0; k < 64; ++k) s += QL[i*64+k]*QL[j*64+k];
    ws[WS_Q + e] = s;
  } else if (idx < 6144) {              // R = RL RL^T + 1e-3 I
    int e = idx - 5120; int i = e >> 5, j = e & 31;
    float s = (i==j) ? 1e-3f : 0.f;
    for (int k = 0; k < 32; ++k) s += RL[i*32+k]*RL[j*32+k];
    ws[WS_R + e] = s;
  }
}

// ============ 2-layer LSTM + softmax head -> w[T][B][16] ============
// One thread per hidden unit computes ALL FOUR gates (4 independent dot
// chains, no gate-buffer round trip). 3 barriers/step (was 7). f32 weights
// read straight from global (rows contiguous -> float4), L2-broadcast.
__global__ __launch_bounds__(512) void lstm_kernel(
    const float* __restrict__ as_,  const float* __restrict__ ws,
    const float* __restrict__ Wih0, const float* __restrict__ Whh0,
    const float* __restrict__ Wih1, const float* __restrict__ Whh1,
    const float* __restrict__ linW, const float* __restrict__ linb,
    float* __restrict__ wout)
{
  const int b = blockIdx.x, tid = threadIdx.x;
  __shared__ __align__(16) float xs[2][32];
  __shared__ __align__(16) float h0[2][128];
  __shared__ __align__(16) float h1[2][128];
  __shared__ __align__(16) float lw[16*128];

  for (int e = tid; e < 2048; e += 512) lw[e] = linW[e];
  if (tid < 128) { h0[0][tid] = 0.f; h1[0][tid] = 0.f; }
  if (tid < 32)  xs[0][tid] = as_[(0*B_SZ + b)*AD + tid];
  float c0 = 0.f, c1 = 0.f;
  float bi0=0,bf0=0,bg0=0,bo0=0, bi1=0,bf1=0,bg1=0,bo1=0;
  if (tid < 128) {
    bi0=ws[WS_B0+tid]; bf0=ws[WS_B0+tid+128]; bg0=ws[WS_B0+tid+256]; bo0=ws[WS_B0+tid+384];
    bi1=ws[WS_B1+tid]; bf1=ws[WS_B1+tid+128]; bg1=ws[WS_B1+tid+256]; bo1=ws[WS_B1+tid+384];
  }
  __syncthreads();

#define DOT4(acc, wv, xv) acc += (wv).x*(xv).x + (wv).y*(xv).y + (wv).z*(xv).z + (wv).w*(xv).w;

  for (int t = 0; t < T_LEN; ++t) {
    const int cp = t & 1, np = cp ^ 1;
    // ---- Phase A: layer 0 (threads 0-127); x prefetch (threads 128-159)
    if (tid < 128) {
      const int h = tid;
      float ai=bi0, af=bf0, ag=bg0, ao=bo0;
      {
        const float4* ri = (const float4*)&Wih0[(h     )*32];
        const float4* rf = (const float4*)&Wih0[(h+128)*32];
        const float4* rg = (const float4*)&Wih0[(h+256)*32];
        const float4* ro = (const float4*)&Wih0[(h+384)*32];
        #pragma unroll
        for (int q = 0; q < 8; ++q) {
          const float4 xv = *(const float4*)&xs[cp][q*4];
          DOT4(ai, ri[q], xv); DOT4(af, rf[q], xv);
          DOT4(ag, rg[q], xv); DOT4(ao, ro[q], xv);
        }
      }
      {
        const float4* ri = (const float4*)&Whh0[(h     )*128];
        const float4* rf = (const float4*)&Whh0[(h+128)*128];
        const float4* rg = (const float4*)&Whh0[(h+256)*128];
        const float4* ro = (const float4*)&Whh0[(h+384)*128];
        #pragma unroll 8
        for (int q = 0; q < 32; ++q) {
          const float4 hv = *(const float4*)&h0[cp][q*4];
          DOT4(ai, ri[q], hv); DOT4(af, rf[q], hv);
          DOT4(ag, rg[q], hv); DOT4(ao, ro[q], hv);
        }
      }
      c0 = sigmoidf_(af)*c0 + sigmoidf_(ai)*tanhf(ag);
      h0[np][h] = sigmoidf_(ao)*tanhf(c0);
    } else if (tid < 160 && t+1 < T_LEN) {
      xs[np][tid-128] = as_[((t+1)*B_SZ + b)*AD + (tid-128)];
    }
    __syncthreads();
    // ---- Phase B: layer 1 (threads 0-127)
    if (tid < 128) {
      const int h = tid;
      float ai=bi1, af=bf1, ag=bg1, ao=bo1;
      {
        const float4* ri = (const float4*)&Wih1[(h     )*128];
        const float4* rf = (const float4*)&Wih1[(h+128)*128];
        const float4* rg = (const float4*)&Wih1[(h+256)*128];
        const float4* ro = (const float4*)&Wih1[(h+384)*128];
        #pragma unroll 8
        for (int q = 0; q < 32; ++q) {
          const float4 hv = *(const float4*)&h0[np][q*4];
          DOT4(ai, ri[q], hv); DOT4(af, rf[q], hv);
          DOT4(ag, rg[q], hv); DOT4(ao, ro[q], hv);
        }
      }
      {
        const float4* ri = (const float4*)&Whh1[(h     )*128];
        const float4* rf = (const float4*)&Whh1[(h+128)*128];
        const float4* rg = (const float4*)&Whh1[(h+256)*128];
        const float4* ro = (const float4*)&Whh1[(h+384)*128];
        #pragma unroll 8
        for (int q = 0; q < 32; ++q) {
          const float4 hv = *(const float4*)&h1[cp][q*4];
          DOT4(ai, ri[q], hv); DOT4(af, rf[q], hv);
          DOT4(ag, rg[q], hv); DOT4(ao, ro[q], hv);
        }
      }
      c1 = sigmoidf_(af)*c1 + sigmoidf_(ai)*tanhf(ag);
      h1[np][h] = sigmoidf_(ao)*tanhf(c1);
    }
    __syncthreads();
    // ---- Phase C: head + softmax, wave 0 (16-lane shfl groups, all active)
    if (tid < 64) {
      const int k = tid & 15;
      float acc = linb[k];
      const float4* lr = (const float4*)&lw[k*128];
      #pragma unroll 8
      for (int q = 0; q < 32; ++q) {
        const float4 hv = *(const float4*)&h1[np][q*4];
        DOT4(acc, lr[q], hv);
      }
      float m = acc;
      m = fmaxf(m, __shfl_xor(m, 1));
      m = fmaxf(m, __shfl_xor(m, 2));
      m = fmaxf(m, __shfl_xor(m, 4));
      m = fmaxf(m, __shfl_xor(m, 8));
      const float e = expf(acc - m);
      float s = e;
      s += __shfl_xor(s, 1); s += __shfl_xor(s, 2);
      s += __shfl_xor(s, 4); s += __shfl_xor(s, 8);
      if (tid < 16) wout[(t*B_SZ + b)*KMIX + k] = e / s;
    }
    __syncthreads();
  }
#undef DOT4
}

// ============ mix ============
__global__ __launch_bounds__(256) void mix_kernel(
    const float* __restrict__ w, const float* __restrict__ AK,
    const float* __restrict__ CK, float* __restrict__ out)
{
  float* matA = out + OUT_MATA;
  float* matC = out + OUT_MATC;
  const int tb0 = blockIdx.x * 16;
  const int tid = threadIdx.x;
  __shared__ float wl[16][16];
  { int lt = tid >> 4, k = tid & 15; wl[lt][k] = w[(tb0 + lt)*16 + k]; }
  __syncthreads();

  for (int e = tid; e < ZD*ZD; e += 256) {
    float v[16];
    #pragma unroll
    for (int u = 0; u < 16; ++u) v[u] = 0.f;
    #pragma unroll 4
    for (int k = 0; k < 16; ++k) {
      float a = AK[k*ZD*ZD + e];
      #pragma unroll
      for (int u = 0; u < 16; ++u) v[u] += wl[u][k] * a;
    }
    #pragma unroll
    for (int u = 0; u < 16; ++u) matA[(size_t)(tb0+u)*(ZD*ZD) + e] = v[u];
  }
  for (int e = tid; e < AD*ZD; e += 256) {
    float v[16];
    #pragma unroll
    for (int u = 0; u < 16; ++u) v[u] = 0.f;
    #pragma unroll 4
    for (int k = 0; k < 16; ++k) {
      float a = CK[k*AD*ZD + e];
      #pragma unroll
      for (int u = 0; u < 16; ++u) v[u] += wl[u][k] * a;
    }
    #pragma unroll
    for (int u = 0; u < 16; ++u) matC[(size_t)(tb0+u)*(AD*ZD) + e] = v[u];
  }
}

// ============ Kalman filter: one block (512 thr, 8 waves) per batch ============
// 7 barriers/step (was 9): explicit symmetrization dropped — cov_t = covp -
// W^T W is symmetric by construction; covnext asymmetry is fp-reorder noise
// (~1e-6 rel), contractive recursion, threshold 1.96. Register discipline per
// r5-r7: phase-local arrays only, no cross-phase prefetch regs.
__global__ __launch_bounds__(512, 1) void kalman_kernel(
    const float* __restrict__ as_, const float* __restrict__ ws,
    float* __restrict__ out)
{
  const int b = blockIdx.x, tid = threadIdx.x;
  const float* Rm = ws + WS_R;
  const float* Qg = ws + WS_Q;
  const float* matA = out + OUT_MATA;
  const float* matC = out + OUT_MATC;
  float* means  = out + OUT_MEANS;
  float* covs   = out + OUT_COVS;
  float* nmeans = out + OUT_NMEANS;
  float* ncovs  = out + OUT_NCOVS;

  __shared__ __align__(16) float covp[64*68];   // aug: col 64 = meanp
  __shared__ __align__(16) float At[2][64*68];  // A^T, double-buffered
  __shared__ __align__(16) float Cm[2][32*68];  // C rows, stride 68 (16B aligned)
  __shared__ __align__(16) float CPm[32*68];    // [CP | Cmeanp - a]
  __shared__ __align__(16) float Wm[32*68];     // L^{-1} CPaug
  __shared__ float Smat[32*36];                 // S -> L (inv diag on diagonal)
  __shared__ __align__(16) float tmpm[64*68];   // A @ covt_aug
  __shared__ __align__(16) float Ql[64*68];     // Q staged

  // ---- init
  for (int e = tid; e < 64*64; e += 512) {
    const int i = e >> 6, j = e & 63;
    Ql[i*68 + j]   = Qg[e];
    covp[i*68 + j] = (i == j) ? 1.f : 0.f;
  }
  if (tid < 64) covp[tid*68 + 64] = 0.f;
  {
    const float* Ag = matA + (size_t)b*4096;
    const float* Cg = matC + (size_t)b*2048;
    for (int e = tid; e < 4096; e += 512) At[0][(e & 63)*68 + (e >> 6)] = Ag[e];
    for (int e = tid; e < 2048; e += 512) Cm[0][(e >> 6)*68 + (e & 63)] = Cg[e];
  }
  __syncthreads();

  const int su = tid - 128;         // staging index 0..383 (waves 2..7)

  int cur = 0;
  for (int t = 0; t < T_LEN; ++t) {
    const int tb = t*B_SZ + b;
    const int nxt = cur ^ 1;
    float areg = 0.f;
    if ((tid & 15) == 15) areg = as_[(size_t)tb*AD + (tid >> 4)];

    // ---- P1: CPaug = C @ covp_aug   (32 rows x 65); float4 a-stream
    {
      const int i = tid >> 4, j0 = (tid & 15)*4;
      const bool do64 = ((tid & 15) == 15);
      const float* Crow = &Cm[cur][i*68];
      float4 acc = make_float4(0,0,0,0); float s64 = 0.f;
      #pragma unroll 4
      for (int k4 = 0; k4 < 16; ++k4) {
        const float4 a4 = *(const float4*)&Crow[k4*4];
        const float4 b0 = *(const float4*)&covp[(k4*4+0)*68 + j0];
        const float4 b1 = *(const float4*)&covp[(k4*4+1)*68 + j0];
        const float4 b2 = *(const float4*)&covp[(k4*4+2)*68 + j0];
        const float4 b3 = *(const float4*)&covp[(k4*4+3)*68 + j0];
        acc.x += a4.x*b0.x + a4.y*b1.x + a4.z*b2.x + a4.w*b3.x;
        acc.y += a4.x*b0.y + a4.y*b1.y + a4.z*b2.y + a4.w*b3.y;
        acc.z += a4.x*b0.z + a4.y*b1.z + a4.z*b2.z + a4.w*b3.z;
        acc.w += a4.x*b0.w + a4.y*b1.w + a4.z*b2.w + a4.w*b3.w;
        if (do64) {
          s64 += a4.x*covp[(k4*4+0)*68+64] + a4.y*covp[(k4*4+1)*68+64]
               + a4.z*covp[(k4*4+2)*68+64] + a4.w*covp[(k4*4+3)*68+64];
        }
      }
      *(float4*)&CPm[i*68 + j0] = acc;
      if (do64) CPm[i*68 + 64] = s64 - areg;   // C meanp - a  (= -innov)
    }
    __syncthreads();
    // ---- P2: S = CP @ C^T + R   (32x32, 2 outputs/thread, all-float4)
    {
      const int i = tid >> 4, j0 = (tid & 15)*2;
      const float* CProw = &CPm[i*68];
      const float* Cr0 = &Cm[cur][(j0+0)*68];
      const float* Cr1 = &Cm[cur][(j0+1)*68];
      float a0 = 0.f, a1 = 0.f;
      #pragma unroll 4
      for (int k4 = 0; k4 < 16; ++k4) {
        const float4 cp4 = *(const float4*)&CProw[k4*4];
        const float4 c04 = *(const float4*)&Cr0[k4*4];
        const float4 c14 = *(const float4*)&Cr1[k4*4];
        a0 += cp4.x*c04.x + cp4.y*c04.y + cp4.z*c04.z + cp4.w*c04.w;
        a1 += cp4.x*c14.x + cp4.y*c14.y + cp4.z*c14.z + cp4.w*c14.w;
      }
      Smat[i*36 + j0+0] = a0 + Rm[i*32 + j0+0];
      Smat[i*36 + j0+1] = a1 + Rm[i*32 + j0+1];
    }
    __syncthreads();
    // ---- P3a: wave 0 Cholesky; waves 2-7 stage t+1 A/C
    {
      const int wv = tid >> 6, lane = tid & 63;
      if (wv == 0) {
        if (lane < 32) {
          float Lr[32];
          float invd = 0.f;   // static select only (runtime Lr[lane] = r3 bug)
          #pragma unroll
          for (int j = 0; j < 32; ++j) Lr[j] = Smat[lane*36 + j];
          #pragma unroll
          for (int k = 0; k < 32; ++k) {
            const float piv = __shfl(Lr[k], k);
            const float ir  = 1.0f / sqrtf(piv);
            const float lik = Lr[k] * ir;
            invd = (lane == k) ? ir : invd;
            #pragma unroll
            for (int j = k+1; j < 32; ++j) {
              const float ljk = __shfl(lik, j);
              Lr[j] -= lik * ljk;
            }
            Lr[k] = lik;
          }
          #pragma unroll
          for (int j = 0; j < 32; ++j)
            if (j < lane) Smat[lane*36 + j] = Lr[j];
          Smat[lane*36 + lane] = invd;
        }
      } else if (wv >= 2 && t < T_LEN-1) {
        const float* Ag = matA + (size_t)(tb+64)*4096;
        const float* Cg = matC + (size_t)(tb+64)*2048;
        const float4 q0 = *(const float4*)&Ag[su*4];                 // A 0..383
        const float4 q1 = *(const float4*)&Ag[(su+384)*4];           // A 384..767
        const float4 q2 = (su < 256) ? *(const float4*)&Ag[(su+768)*4]
                                     : *(const float4*)&Cg[(su-256)*4];
        const float4 q3 = *(const float4*)&Cg[(su+128)*4];           // C 128..511
        { const int c = su;       const int i = c>>4, j = (c&15)*4;
          At[nxt][(j+0)*68+i]=q0.x; At[nxt][(j+1)*68+i]=q0.y; At[nxt][(j+2)*68+i]=q0.z; At[nxt][(j+3)*68+i]=q0.w; }
        { const int c = su + 384; const int i = c>>4, j = (c&15)*4;
          At[nxt][(j+0)*68+i]=q1.x; At[nxt][(j+1)*68+i]=q1.y; At[nxt][(j+2)*68+i]=q1.z; At[nxt][(j+3)*68+i]=q1.w; }
        if (su < 256) { const int c = su + 768; const int i = c>>4, j = (c&15)*4;
          At[nxt][(j+0)*68+i]=q2.x; At[nxt][(j+1)*68+i]=q2.y; At[nxt][(j+2)*68+i]=q2.z; At[nxt][(j+3)*68+i]=q2.w; }
        else { const int cc = su - 256; *(float4*)&Cm[nxt][(cc>>4)*68 + (cc&15)*4] = q2; }
        { const int cc = su + 128;      *(float4*)&Cm[nxt][(cc>>4)*68 + (cc&15)*4] = q3; }
      }
    }
    __syncthreads();
    // ---- P3b: forward solve W = L^{-1} CPaug, one column per thread
    if (tid < 65) {
      const int c = tid;
      float s[32];
      #pragma unroll
      for (int i = 0; i < 32; ++i) s[i] = CPm[i*68 + c];
      #pragma unroll
      for (int k = 0; k < 32; ++k) {
        const float y = s[k] * Smat[k*36 + k];     // diag holds 1/L[k][k]
        Wm[k*68 + c] = y;
        #pragma unroll
        for (int i = k+1; i < 32; ++i)
          s[i] -= Smat[i*36 + k] * y;
      }
    }
    __syncthreads();
    // ---- P5: covt_aug = covp_aug - W^T W (in place); write covs, means
    {
      const int j = tid >> 3, c0 = (tid & 7)*8;
      const bool do64 = ((tid & 7) == 7);
      float4 a0 = make_float4(0,0,0,0), a1 = a0; float s64 = 0.f;
      #pragma unroll 8
      for (int k = 0; k < 32; ++k) {
        const float a = Wm[k*68 + j];
        const float4 b0 = *(const float4*)&Wm[k*68 + c0];
        const float4 b1 = *(const float4*)&Wm[k*68 + c0 + 4];
        a0.x += a*b0.x; a0.y += a*b0.y; a0.z += a*b0.z; a0.w += a*b0.w;
        a1.x += a*b1.x; a1.y += a*b1.y; a1.z += a*b1.z; a1.w += a*b1.w;
        if (do64) s64 += a * Wm[k*68 + 64];
      }
      float4 c4a = *(const float4*)&covp[j*68 + c0];
      float4 c4b = *(const float4*)&covp[j*68 + c0 + 4];
      c4a.x -= a0.x; c4a.y -= a0.y; c4a.z -= a0.z; c4a.w -= a0.w;
      c4b.x -= a1.x; c4b.y -= a1.y; c4b.z -= a1.z; c4b.w -= a1.w;
      *(float4*)&covp[j*68 + c0]     = c4a;
      *(float4*)&covp[j*68 + c0 + 4] = c4b;
      *(float4*)&covs[(size_t)tb*4096 + j*64 + c0]     = c4a;
      *(float4*)&covs[(size_t)tb*4096 + j*64 + c0 + 4] = c4b;
      if (do64) {
        const float mt = covp[j*68 + 64] - s64;   // mean_t
        covp[j*68 + 64] = mt;
        means[(size_t)tb*64 + j] = mt;
      }
    }
    __syncthreads();
    // ---- P6: tmpm = A @ covt_aug ; col64 = mean_next
    {
      const int i = tid >> 3, c0 = (tid & 7)*8;
      const bool do64 = ((tid & 7) == 7);
      const float* Atb = At[cur];
      float4 a0 = make_float4(0,0,0,0), a1 = a0; float s64 = 0.f;
      #pragma unroll 8
      for (int k = 0; k < 64; ++k) {
        const float a = Atb[k*68 + i];
        const float4 b0 = *(const float4*)&covp[k*68 + c0];
        const float4 b1 = *(const float4*)&covp[k*68 + c0 + 4];
        a0.x += a*b0.x; a0.y += a*b0.y; a0.z += a*b0.z; a0.w += a*b0.w;
        a1.x += a*b1.x; a1.y += a*b1.y; a1.z += a*b1.z; a1.w += a*b1.w;
        if (do64) s64 += a * covp[k*68 + 64];
      }
      *(float4*)&tmpm[i*68 + c0]     = a0;
      *(float4*)&tmpm[i*68 + c0 + 4] = a1;
      if (do64) {
        tmpm[i*68 + 64] = s64;
        nmeans[(size_t)tb*64 + i] = s64;
      }
    }
    __syncthreads();
    // ---- P7: covnext = tmpm @ A^T + Q -> covp (NO sym); write ncovs
    {
      const int i = tid >> 3, j0 = (tid & 7)*8;
      const float* Atb  = At[cur];
      const float* trow = &tmpm[i*68];
      float4 a0 = make_float4(0,0,0,0), a1 = a0;
      #pragma unroll 4
      for (int k4 = 0; k4 < 16; ++k4) {
        const float4 t4 = *(const float4*)&trow[k4*4];
        #pragma unroll
        for (int m = 0; m < 4; ++m) {
          const float a = (m==0)?t4.x:(m==1)?t4.y:(m==2)?t4.z:t4.w;
          const float4 b0 = *(const float4*)&Atb[(k4*4+m)*68 + j0];
          const float4 b1 = *(const float4*)&Atb[(k4*4+m)*68 + j0 + 4];
          a0.x += a*b0.x; a0.y += a*b0.y; a0.z += a*b0.z; a0.w += a*b0.w;
          a1.x += a*b1.x; a1.y += a*b1.y; a1.z += a*b1.z; a1.w += a*b1.w;
        }
      }
      const float4 q0 = *(const float4*)&Ql[i*68 + j0];
      const float4 q1 = *(const float4*)&Ql[i*68 + j0 + 4];
      a0.x += q0.x; a0.y += q0.y; a0.z += q0.z; a0.w += q0.w;
      a1.x += q1.x; a1.y += q1.y; a1.z += q1.z; a1.w += q1.w;
      *(float4*)&covp[i*68 + j0]     = a0;
      *(float4*)&covp[i*68 + j0 + 4] = a1;
      *(float4*)&ncovs[(size_t)tb*4096 + i*64 + j0]     = a0;
      *(float4*)&ncovs[(size_t)tb*4096 + i*64 + j0 + 4] = a1;
      if ((tid & 7) == 7) covp[i*68 + 64] = tmpm[i*68 + 64];
    }
    __syncthreads();
    cur = nxt;
  }
}

extern "C" void kernel_launch(void* const* d_in, const int* in_sizes, int n_in,
                              void* d_out, int out_size, void* d_ws, size_t ws_size,
                              hipStream_t stream) {
  const float* as_  = (const float*)d_in[0];
  const float* AK   = (const float*)d_in[1];
  const float* CK   = (const float*)d_in[2];
  const float* QL   = (const float*)d_in[3];
  const float* RL   = (const float*)d_in[4];
  const float* linW = (const float*)d_in[5];
  const float* linb = (const float*)d_in[6];
  const float* Wih0 = (const float*)d_in[7];
  const float* Whh0 = (const float*)d_in[8];
  const float* bih0 = (const float*)d_in[9];
  const float* bhh0 = (const float*)d_in[10];
  const float* Wih1 = (const float*)d_in[11];
  const float* Whh1 = (const float*)d_in[12];
  const float* bih1 = (const float*)d_in[13];
  const float* bhh1 = (const float*)d_in[14];
  float* out = (float*)d_out;
  float* ws  = (float*)d_ws;

  prep_kernel<<<24, 256, 0, stream>>>(bih0, bhh0, bih1, bhh1, QL, RL, ws);
  lstm_kernel<<<B_SZ, 512, 0, stream>>>(as_, ws, Wih0, Whh0, Wih1, Whh1,
                                        linW, linb, ws + WS_W);
  mix_kernel<<<(T_LEN*B_SZ)/16, 256, 0, stream>>>(ws + WS_W, AK, CK, out);
  kalman_kernel<<<B_SZ, 512, 0, stream>>>(as_, ws, out);
}

// Round 9
// 4219.471 us; speedup vs baseline: 1.5813x; 1.5813x over previous
//
#include <hip/hip_runtime.h>
#include <math.h>

// Problem dims
#define T_LEN 128
#define B_SZ  64
#define AD    32
#define ZD    64
#define KMIX  16
#define HID   128

// ---------------- workspace layout ----------------
// bf16 weights (ushort), packed [K/2][512][2] per matrix (COALESCED: lane=gate):
//   W0IH ushort ofs 0      (16384)
//   W0HH ushort ofs 16384  (65536)
//   W1IH ushort ofs 81920  (65536)
//   W1HH ushort ofs 147456 (65536)
// float region (offsets in floats):
#define WS_B0 106496
#define WS_B1 107008
#define WS_Q  107520
#define WS_R  111616
#define WS_W  112640

// ---------------- output layout (floats) ----------------
#define OUT_MEANS   0
#define OUT_COVS    524288
#define OUT_NMEANS  34078720
#define OUT_NCOVS   34603008
#define OUT_MATA    68157440
#define OUT_MATC    101711872

__device__ __forceinline__ float sigmoidf_(float x){ return 1.0f/(1.0f + expf(-x)); }

__device__ __forceinline__ unsigned short f2bf(float f){
  unsigned u = __float_as_uint(f);
  u += 0x7FFFu + ((u >> 16) & 1u);
  return (unsigned short)(u >> 16);
}

// ============ prep: pack LSTM weights bf16 [k/2][512][2], biases, Q, R ============
__global__ __launch_bounds__(256) void prep_kernel(
    const float* __restrict__ Wih0, const float* __restrict__ Whh0,
    const float* __restrict__ bih0, const float* __restrict__ bhh0,
    const float* __restrict__ Wih1, const float* __restrict__ Whh1,
    const float* __restrict__ bih1, const float* __restrict__ bhh1,
    const float* __restrict__ QL,   const float* __restrict__ RL,
    float* __restrict__ ws)
{
  int idx = blockIdx.x*256 + threadIdx.x;
  unsigned short* w16 = (unsigned short*)ws;
  if (idx < 212992) {
    const float* src; int local, base, IN;
    if (idx < 16384)       { src = Wih0; local = idx;          base = 0;      IN = 32; }
    else if (idx < 81920)  { src = Whh0; local = idx - 16384;  base = 16384;  IN = 128; }
    else if (idx < 147456) { src = Wih1; local = idx - 81920;  base = 81920;  IN = 128; }
    else                   { src = Whh1; local = idx - 147456; base = 147456; IN = 128; }
    int pair = local >> 10, g = (local >> 1) & 511, lo = local & 1;
    int k = pair*2 + lo;
    w16[base + local] = f2bf(src[g*IN + k]);
  } else if (idx < 213504) {
    int g = idx - 212992; ws[WS_B0 + g] = bih0[g] + bhh0[g];
  } else if (idx < 214016) {
    int g = idx - 213504; ws[WS_B1 + g] = bih1[g] + bhh1[g];
  } else if (idx < 218112) {              // Q = QL QL^T + 1e-3 I
    int e = idx - 214016; int i = e >> 6, j = e & 63;
    float s = (i==j) ? 1e-3f : 0.f;
    for (int k = 0; k < 64; ++k) s += QL[i*64+k]*QL[j*64+k];
    ws[WS_Q + e] = s;
  } else if (idx < 219136) {              // R = RL RL^T + 1e-3 I
    int e = idx - 218112; int i = e >> 5, j = e & 31;
    float s = (i==j) ? 1e-3f : 0.f;
    for (int k = 0; k < 32; ++k) s += RL[i*32+k]*RL[j*32+k];
    ws[WS_R + e] = s;
  }
}

// ============ 2-layer LSTM + softmax head -> w[T][B][16] ============
// COALESCED bf16 weight reads (W[k][tid] — lane-consecutive; the r8 row-major
// per-thread design was 64 cache lines/instr, 3.5x slower). 4 barriers/step
// (was 7): act0 fused with x-prefetch; head+softmax one all-lane shfl phase
// with no trailing barrier (nothing it reads is overwritten before B1(t+1)).
__global__ __launch_bounds__(512) void lstm_kernel(
    const float* __restrict__ as_, const float* __restrict__ ws,
    const float* __restrict__ linW, const float* __restrict__ linb,
    float* __restrict__ wout)
{
  const int b = blockIdx.x, tid = threadIdx.x;
  const unsigned* W0ih = (const unsigned*)ws;        // [16][512] pairs
  const unsigned* W0hh = W0ih + 16*512;              // [64][512]
  const unsigned* W1ih = W0hh + 64*512;              // [64][512]
  const unsigned* W1hh = W1ih + 64*512;              // [64][512]

  __shared__ float xs[2][32];
  __shared__ float h0[128];
  __shared__ float h1[128];
  __shared__ float gbuf[512];
  __shared__ float lw[16*132];                        // linW, pad-132 rows

  for (int e = tid; e < 2048; e += 512) lw[(e >> 7)*132 + (e & 127)] = linW[e];
  if (tid < 128) { h0[tid] = 0.f; h1[tid] = 0.f; }
  if (tid < 32)  xs[0][tid] = as_[(0*B_SZ + b)*AD + tid];
  float c0 = 0.f, c1 = 0.f;
  const float bias0 = ws[WS_B0 + tid];
  const float bias1 = ws[WS_B1 + tid];
  const float lbk = linb[tid & 15];
  __syncthreads();

  for (int t = 0; t < T_LEN; ++t) {
    const int cp = t & 1, np = cp ^ 1;
    { // gates layer 0: all 512 threads, one gate each
      float acc = bias0;
      #pragma unroll 4
      for (int kk = 0; kk < 16; ++kk) {
        const unsigned u = W0ih[kk*512 + tid];
        acc += __uint_as_float(u << 16) * xs[cp][2*kk]
             + __uint_as_float(u & 0xFFFF0000u) * xs[cp][2*kk+1];
      }
      #pragma unroll 8
      for (int kk = 0; kk < 64; ++kk) {
        const unsigned u = W0hh[kk*512 + tid];
        acc += __uint_as_float(u << 16) * h0[2*kk]
             + __uint_as_float(u & 0xFFFF0000u) * h0[2*kk+1];
      }
      gbuf[tid] = acc;
    }
    __syncthreads();                                  // B1
    // act0 (0-127) + next-x prefetch (128-159)
    if (tid < 128) {
      float ig = sigmoidf_(gbuf[tid]);
      float fg = sigmoidf_(gbuf[tid+128]);
      float gg = tanhf(gbuf[tid+256]);
      float og = sigmoidf_(gbuf[tid+384]);
      c0 = fg*c0 + ig*gg;
      h0[tid] = og * tanhf(c0);
    } else if (tid < 160 && t+1 < T_LEN) {
      xs[np][tid-128] = as_[((t+1)*B_SZ + b)*AD + (tid-128)];
    }
    __syncthreads();                                  // B2
    { // gates layer 1: all 512 threads
      float acc = bias1;
      #pragma unroll 8
      for (int kk = 0; kk < 64; ++kk) {
        const unsigned u = W1ih[kk*512 + tid];
        acc += __uint_as_float(u << 16) * h0[2*kk]
             + __uint_as_float(u & 0xFFFF0000u) * h0[2*kk+1];
      }
      #pragma unroll 8
      for (int kk = 0; kk < 64; ++kk) {
        const unsigned u = W1hh[kk*512 + tid];
        acc += __uint_as_float(u << 16) * h1[2*kk]
             + __uint_as_float(u & 0xFFFF0000u) * h1[2*kk+1];
      }
      gbuf[tid] = acc;
    }
    __syncthreads();                                  // B3
    if (tid < 128) {
      float ig = sigmoidf_(gbuf[tid]);
      float fg = sigmoidf_(gbuf[tid+128]);
      float gg = tanhf(gbuf[tid+256]);
      float og = sigmoidf_(gbuf[tid+384]);
      c1 = fg*c1 + ig*gg;
      h1[tid] = og * tanhf(c1);
    }
    __syncthreads();                                  // B4
    // head + softmax: wave 0 only (64 lanes, all active through shfls).
    // Lane = q*16 + k: partial dot over h1[q*32..q*32+31], reduce across q
    // (xor 16,32), then softmax across k (xor 1,2,4,8). No trailing barrier:
    // h1/gbuf are not rewritten until after B1/B3 of t+1.
    if (tid < 64) {
      const int k = tid & 15, q = tid >> 4;
      float acc = 0.f;
      const float* lr = &lw[k*132 + q*32];
      const float* hr = &h1[q*32];
      #pragma unroll 8
      for (int j = 0; j < 32; ++j) acc += lr[j] * hr[j];
      acc += __shfl_xor(acc, 16);
      acc += __shfl_xor(acc, 32);
      const float logit = acc + lbk;
      float m = logit;
      m = fmaxf(m, __shfl_xor(m, 1));
      m = fmaxf(m, __shfl_xor(m, 2));
      m = fmaxf(m, __shfl_xor(m, 4));
      m = fmaxf(m, __shfl_xor(m, 8));
      const float e = expf(logit - m);
      float s = e;
      s += __shfl_xor(s, 1); s += __shfl_xor(s, 2);
      s += __shfl_xor(s, 4); s += __shfl_xor(s, 8);
      if (tid < 16) wout[(t*B_SZ + b)*KMIX + k] = e / s;
    }
  }
}

// ============ mix ============
__global__ __launch_bounds__(256) void mix_kernel(
    const float* __restrict__ w, const float* __restrict__ AK,
    const float* __restrict__ CK, float* __restrict__ out)
{
  float* matA = out + OUT_MATA;
  float* matC = out + OUT_MATC;
  const int tb0 = blockIdx.x * 16;
  const int tid = threadIdx.x;
  __shared__ float wl[16][16];
  { int lt = tid >> 4, k = tid & 15; wl[lt][k] = w[(tb0 + lt)*16 + k]; }
  __syncthreads();

  for (int e = tid; e < ZD*ZD; e += 256) {
    float v[16];
    #pragma unroll
    for (int u = 0; u < 16; ++u) v[u] = 0.f;
    #pragma unroll 4
    for (int k = 0; k < 16; ++k) {
      float a = AK[k*ZD*ZD + e];
      #pragma unroll
      for (int u = 0; u < 16; ++u) v[u] += wl[u][k] * a;
    }
    #pragma unroll
    for (int u = 0; u < 16; ++u) matA[(size_t)(tb0+u)*(ZD*ZD) + e] = v[u];
  }
  for (int e = tid; e < AD*ZD; e += 256) {
    float v[16];
    #pragma unroll
    for (int u = 0; u < 16; ++u) v[u] = 0.f;
    #pragma unroll 4
    for (int k = 0; k < 16; ++k) {
      float a = CK[k*AD*ZD + e];
      #pragma unroll
      for (int u = 0; u < 16; ++u) v[u] += wl[u][k] * a;
    }
    #pragma unroll
    for (int u = 0; u < 16; ++u) matC[(size_t)(tb0+u)*(AD*ZD) + e] = v[u];
  }
}

// ============ Kalman filter: one block (512 thr, 8 waves) per batch ============
// 7 barriers/step: explicit symmetrization dropped (cov_t = covp - W^T W is
// symmetric by construction; covnext asymmetry is fp-reorder noise).
// Register discipline per r5-r7: phase-local arrays only, no cross-phase
// prefetch regs, no runtime indexing of per-thread arrays.
__global__ __launch_bounds__(512, 1) void kalman_kernel(
    const float* __restrict__ as_, const float* __restrict__ ws,
    float* __restrict__ out)
{
  const int b = blockIdx.x, tid = threadIdx.x;
  const float* Rm = ws + WS_R;
  const float* Qg = ws + WS_Q;
  const float* matA = out + OUT_MATA;
  const float* matC = out + OUT_MATC;
  float* means  = out + OUT_MEANS;
  float* covs   = out + OUT_COVS;
  float* nmeans = out + OUT_NMEANS;
  float* ncovs  = out + OUT_NCOVS;

  __shared__ __align__(16) float covp[64*68];   // aug: col 64 = meanp
  __shared__ __align__(16) float At[2][64*68];  // A^T, double-buffered
  __shared__ __align__(16) float Cm[2][32*68];  // C rows, stride 68 (16B aligned)
  __shared__ __align__(16) float CPm[32*68];    // [CP | Cmeanp - a]
  __shared__ __align__(16) float Wm[32*68];     // L^{-1} CPaug
  __shared__ float Smat[32*36];                 // S -> L (inv diag on diagonal)
  __shared__ __align__(16) float tmpm[64*68];   // A @ covt_aug
  __shared__ __align__(16) float Ql[64*68];     // Q staged

  // ---- init
  for (int e = tid; e < 64*64; e += 512) {
    const int i = e >> 6, j = e & 63;
    Ql[i*68 + j]   = Qg[e];
    covp[i*68 + j] = (i == j) ? 1.f : 0.f;
  }
  if (tid < 64) covp[tid*68 + 64] = 0.f;
  {
    const float* Ag = matA + (size_t)b*4096;
    const float* Cg = matC + (size_t)b*2048;
    for (int e = tid; e < 4096; e += 512) At[0][(e & 63)*68 + (e >> 6)] = Ag[e];
    for (int e = tid; e < 2048; e += 512) Cm[0][(e >> 6)*68 + (e & 63)] = Cg[e];
  }
  __syncthreads();

  const int su = tid - 128;         // staging index 0..383 (waves 2..7)

  int cur = 0;
  for (int t = 0; t < T_LEN; ++t) {
    const int tb = t*B_SZ + b;
    const int nxt = cur ^ 1;
    float areg = 0.f;
    if ((tid & 15) == 15) areg = as_[(size_t)tb*AD + (tid >> 4)];

    // ---- P1: CPaug = C @ covp_aug   (32 rows x 65); float4 a-stream
    {
      const int i = tid >> 4, j0 = (tid & 15)*4;
      const bool do64 = ((tid & 15) == 15);
      const float* Crow = &Cm[cur][i*68];
      float4 acc = make_float4(0,0,0,0); float s64 = 0.f;
      #pragma unroll 4
      for (int k4 = 0; k4 < 16; ++k4) {
        const float4 a4 = *(const float4*)&Crow[k4*4];
        const float4 b0 = *(const float4*)&covp[(k4*4+0)*68 + j0];
        const float4 b1 = *(const float4*)&covp[(k4*4+1)*68 + j0];
        const float4 b2 = *(const float4*)&covp[(k4*4+2)*68 + j0];
        const float4 b3 = *(const float4*)&covp[(k4*4+3)*68 + j0];
        acc.x += a4.x*b0.x + a4.y*b1.x + a4.z*b2.x + a4.w*b3.x;
        acc.y += a4.x*b0.y + a4.y*b1.y + a4.z*b2.y + a4.w*b3.y;
        acc.z += a4.x*b0.z + a4.y*b1.z + a4.z*b2.z + a4.w*b3.z;
        acc.w += a4.x*b0.w + a4.y*b1.w + a4.z*b2.w + a4.w*b3.w;
        if (do64) {
          s64 += a4.x*covp[(k4*4+0)*68+64] + a4.y*covp[(k4*4+1)*68+64]
               + a4.z*covp[(k4*4+2)*68+64] + a4.w*covp[(k4*4+3)*68+64];
        }
      }
      *(float4*)&CPm[i*68 + j0] = acc;
      if (do64) CPm[i*68 + 64] = s64 - areg;   // C meanp - a  (= -innov)
    }
    __syncthreads();
    // ---- P2: S = CP @ C^T + R   (32x32, 2 outputs/thread, all-float4)
    {
      const int i = tid >> 4, j0 = (tid & 15)*2;
      const float* CProw = &CPm[i*68];
      const float* Cr0 = &Cm[cur][(j0+0)*68];
      const float* Cr1 = &Cm[cur][(j0+1)*68];
      float a0 = 0.f, a1 = 0.f;
      #pragma unroll 4
      for (int k4 = 0; k4 < 16; ++k4) {
        const float4 cp4 = *(const float4*)&CProw[k4*4];
        const float4 c04 = *(const float4*)&Cr0[k4*4];
        const float4 c14 = *(const float4*)&Cr1[k4*4];
        a0 += cp4.x*c04.x + cp4.y*c04.y + cp4.z*c04.z + cp4.w*c04.w;
        a1 += cp4.x*c14.x + cp4.y*c14.y + cp4.z*c14.z + cp4.w*c14.w;
      }
      Smat[i*36 + j0+0] = a0 + Rm[i*32 + j0+0];
      Smat[i*36 + j0+1] = a1 + Rm[i*32 + j0+1];
    }
    __syncthreads();
    // ---- P3a: wave 0 Cholesky; waves 2-7 stage t+1 A/C
    {
      const int wv = tid >> 6, lane = tid & 63;
      if (wv == 0) {
        if (lane < 32) {
          float Lr[32];
          float invd = 0.f;   // static select only (runtime Lr[lane] = r3 bug)
          #pragma unroll
          for (int j = 0; j < 32; ++j) Lr[j] = Smat[lane*36 + j];
          #pragma unroll
          for (int k = 0; k < 32; ++k) {
            const float piv = __shfl(Lr[k], k);
            const float ir  = 1.0f / sqrtf(piv);
            const float lik = Lr[k] * ir;
            invd = (lane == k) ? ir : invd;
            #pragma unroll
            for (int j = k+1; j < 32; ++j) {
              const float ljk = __shfl(lik, j);
              Lr[j] -= lik * ljk;
            }
            Lr[k] = lik;
          }
          #pragma unroll
          for (int j = 0; j < 32; ++j)
            if (j < lane) Smat[lane*36 + j] = Lr[j];
          Smat[lane*36 + lane] = invd;
        }
      } else if (wv >= 2 && t < T_LEN-1) {
        const float* Ag = matA + (size_t)(tb+64)*4096;
        const float* Cg = matC + (size_t)(tb+64)*2048;
        const float4 q0 = *(const float4*)&Ag[su*4];                 // A 0..383
        const float4 q1 = *(const float4*)&Ag[(su+384)*4];           // A 384..767
        const float4 q2 = (su < 256) ? *(const float4*)&Ag[(su+768)*4]
                                     : *(const float4*)&Cg[(su-256)*4];
        const float4 q3 = *(const float4*)&Cg[(su+128)*4];           // C 128..511
        { const int c = su;       const int i = c>>4, j = (c&15)*4;
          At[nxt][(j+0)*68+i]=q0.x; At[nxt][(j+1)*68+i]=q0.y; At[nxt][(j+2)*68+i]=q0.z; At[nxt][(j+3)*68+i]=q0.w; }
        { const int c = su + 384; const int i = c>>4, j = (c&15)*4;
          At[nxt][(j+0)*68+i]=q1.x; At[nxt][(j+1)*68+i]=q1.y; At[nxt][(j+2)*68+i]=q1.z; At[nxt][(j+3)*68+i]=q1.w; }
        if (su < 256) { const int c = su + 768; const int i = c>>4, j = (c&15)*4;
          At[nxt][(j+0)*68+i]=q2.x; At[nxt][(j+1)*68+i]=q2.y; At[nxt][(j+2)*68+i]=q2.z; At[nxt][(j+3)*68+i]=q2.w; }
        else { const int cc = su - 256; *(float4*)&Cm[nxt][(cc>>4)*68 + (cc&15)*4] = q2; }
        { const int cc = su + 128;      *(float4*)&Cm[nxt][(cc>>4)*68 + (cc&15)*4] = q3; }
      }
    }
    __syncthreads();
    // ---- P3b: forward solve W = L^{-1} CPaug, one column per thread
    if (tid < 65) {
      const int c = tid;
      float s[32];
      #pragma unroll
      for (int i = 0; i < 32; ++i) s[i] = CPm[i*68 + c];
      #pragma unroll
      for (int k = 0; k < 32; ++k) {
        const float y = s[k] * Smat[k*36 + k];     // diag holds 1/L[k][k]
        Wm[k*68 + c] = y;
        #pragma unroll
        for (int i = k+1; i < 32; ++i)
          s[i] -= Smat[i*36 + k] * y;
      }
    }
    __syncthreads();
    // ---- P5: covt_aug = covp_aug - W^T W (in place); write covs, means
    {
      const int j = tid >> 3, c0 = (tid & 7)*8;
      const bool do64 = ((tid & 7) == 7);
      float4 a0 = make_float4(0,0,0,0), a1 = a0; float s64 = 0.f;
      #pragma unroll 8
      for (int k = 0; k < 32; ++k) {
        const float a = Wm[k*68 + j];
        const float4 b0 = *(const float4*)&Wm[k*68 + c0];
        const float4 b1 = *(const float4*)&Wm[k*68 + c0 + 4];
        a0.x += a*b0.x; a0.y += a*b0.y; a0.z += a*b0.z; a0.w += a*b0.w;
        a1.x += a*b1.x; a1.y += a*b1.y; a1.z += a*b1.z; a1.w += a*b1.w;
        if (do64) s64 += a * Wm[k*68 + 64];
      }
      float4 c4a = *(const float4*)&covp[j*68 + c0];
      float4 c4b = *(const float4*)&covp[j*68 + c0 + 4];
      c4a.x -= a0.x; c4a.y -= a0.y; c4a.z -= a0.z; c4a.w -= a0.w;
      c4b.x -= a1.x; c4b.y -= a1.y; c4b.z -= a1.z; c4b.w -= a1.w;
      *(float4*)&covp[j*68 + c0]     = c4a;
      *(float4*)&covp[j*68 + c0 + 4] = c4b;
      *(float4*)&covs[(size_t)tb*4096 + j*64 + c0]     = c4a;
      *(float4*)&covs[(size_t)tb*4096 + j*64 + c0 + 4] = c4b;
      if (do64) {
        const float mt = covp[j*68 + 64] - s64;   // mean_t
        covp[j*68 + 64] = mt;
        means[(size_t)tb*64 + j] = mt;
      }
    }
    __syncthreads();
    // ---- P6: tmpm = A @ covt_aug ; col64 = mean_next
    {
      const int i = tid >> 3, c0 = (tid & 7)*8;
      const bool do64 = ((tid & 7) == 7);
      const float* Atb = At[cur];
      float4 a0 = make_float4(0,0,0,0), a1 = a0; float s64 = 0.f;
      #pragma unroll 8
      for (int k = 0; k < 64; ++k) {
        const float a = Atb[k*68 + i];
        const float4 b0 = *(const float4*)&covp[k*68 + c0];
        const float4 b1 = *(const float4*)&covp[k*68 + c0 + 4];
        a0.x += a*b0.x; a0.y += a*b0.y; a0.z += a*b0.z; a0.w += a*b0.w;
        a1.x += a*b1.x; a1.y += a*b1.y; a1.z += a*b1.z; a1.w += a*b1.w;
        if (do64) s64 += a * covp[k*68 + 64];
      }
      *(float4*)&tmpm[i*68 + c0]     = a0;
      *(float4*)&tmpm[i*68 + c0 + 4] = a1;
      if (do64) {
        tmpm[i*68 + 64] = s64;
        nmeans[(size_t)tb*64 + i] = s64;
      }
    }
    __syncthreads();
    // ---- P7: covnext = tmpm @ A^T + Q -> covp (NO sym); write ncovs
    {
      const int i = tid >> 3, j0 = (tid & 7)*8;
      const float* Atb  = At[cur];
      const float* trow = &tmpm[i*68];
      float4 a0 = make_float4(0,0,0,0), a1 = a0;
      #pragma unroll 4
      for (int k4 = 0; k4 < 16; ++k4) {
        const float4 t4 = *(const float4*)&trow[k4*4];
        #pragma unroll
        for (int m = 0; m < 4; ++m) {
          const float a = (m==0)?t4.x:(m==1)?t4.y:(m==2)?t4.z:t4.w;
          const float4 b0 = *(const float4*)&Atb[(k4*4+m)*68 + j0];
          const float4 b1 = *(const float4*)&Atb[(k4*4+m)*68 + j0 + 4];
          a0.x += a*b0.x; a0.y += a*b0.y; a0.z += a*b0.z; a0.w += a*b0.w;
          a1.x += a*b1.x; a1.y += a*b1.y; a1.z += a*b1.z; a1.w += a*b1.w;
        }
      }
      const float4 q0 = *(const float4*)&Ql[i*68 + j0];
      const float4 q1 = *(const float4*)&Ql[i*68 + j0 + 4];
      a0.x += q0.x; a0.y += q0.y; a0.z += q0.z; a0.w += q0.w;
      a1.x += q1.x; a1.y += q1.y; a1.z += q1.z; a1.w += q1.w;
      *(float4*)&covp[i*68 + j0]     = a0;
      *(float4*)&covp[i*68 + j0 + 4] = a1;
      *(float4*)&ncovs[(size_t)tb*4096 + i*64 + j0]     = a0;
      *(float4*)&ncovs[(size_t)tb*4096 + i*64 + j0 + 4] = a1;
      if ((tid & 7) == 7) covp[i*68 + 64] = tmpm[i*68 + 64];
    }
    __syncthreads();
    cur = nxt;
  }
}

extern "C" void kernel_launch(void* const* d_in, const int* in_sizes, int n_in,
                              void* d_out, int out_size, void* d_ws, size_t ws_size,
                              hipStream_t stream) {
  const float* as_  = (const float*)d_in[0];
  const float* AK   = (const float*)d_in[1];
  const float* CK   = (const float*)d_in[2];
  const float* QL   = (const float*)d_in[3];
  const float* RL   = (const float*)d_in[4];
  const float* linW = (const float*)d_in[5];
  const float* linb = (const float*)d_in[6];
  const float* Wih0 = (const float*)d_in[7];
  const float* Whh0 = (const float*)d_in[8];
  const float* bih0 = (const float*)d_in[9];
  const float* bhh0 = (const float*)d_in[10];
  const float* Wih1 = (const float*)d_in[11];
  const float* Whh1 = (const float*)d_in[12];
  const float* bih1 = (const float*)d_in[13];
  const float* bhh1 = (const float*)d_in[14];
  float* out = (float*)d_out;
  float* ws  = (float*)d_ws;

  prep_kernel<<<856, 256, 0, stream>>>(Wih0, Whh0, bih0, bhh0,
                                       Wih1, Whh1, bih1, bhh1, QL, RL, ws);
  lstm_kernel<<<B_SZ, 512, 0, stream>>>(as_, ws, linW, linb, ws + WS_W);
  mix_kernel<<<(T_LEN*B_SZ)/16, 256, 0, stream>>>(ws + WS_W, AK, CK, out);
  kalman_kernel<<<B_SZ, 512, 0, stream>>>(as_, ws, out);
}

// Round 10
// 4145.412 us; speedup vs baseline: 1.6096x; 1.0179x over previous
//
#include <hip/hip_runtime.h>
#include <math.h>

// Problem dims
#define T_LEN 128
#define B_SZ  64
#define AD    32
#define ZD    64
#define KMIX  16
#define HID   128

// ---------------- workspace layout ----------------
// bf16 weights (ushort), packed [K/2][512][2] per matrix (COALESCED: lane=gate):
//   W0IH ushort ofs 0      (16384)
//   W0HH ushort ofs 16384  (65536)
//   W1IH ushort ofs 81920  (65536)
//   W1HH ushort ofs 147456 (65536)
// float region (offsets in floats):
#define WS_B0 106496
#define WS_B1 107008
#define WS_Q  107520
#define WS_R  111616
#define WS_W  112640

// ---------------- output layout (floats) ----------------
#define OUT_MEANS   0
#define OUT_COVS    524288
#define OUT_NMEANS  34078720
#define OUT_NCOVS   34603008
#define OUT_MATA    68157440
#define OUT_MATC    101711872

__device__ __forceinline__ float sigmoidf_(float x){ return 1.0f/(1.0f + expf(-x)); }

__device__ __forceinline__ unsigned short f2bf(float f){
  unsigned u = __float_as_uint(f);
  u += 0x7FFFu + ((u >> 16) & 1u);
  return (unsigned short)(u >> 16);
}

// ============ prep: pack LSTM weights bf16 [k/2][512][2], biases, Q, R ============
__global__ __launch_bounds__(256) void prep_kernel(
    const float* __restrict__ Wih0, const float* __restrict__ Whh0,
    const float* __restrict__ bih0, const float* __restrict__ bhh0,
    const float* __restrict__ Wih1, const float* __restrict__ Whh1,
    const float* __restrict__ bih1, const float* __restrict__ bhh1,
    const float* __restrict__ QL,   const float* __restrict__ RL,
    float* __restrict__ ws)
{
  int idx = blockIdx.x*256 + threadIdx.x;
  unsigned short* w16 = (unsigned short*)ws;
  if (idx < 212992) {
    const float* src; int local, base, IN;
    if (idx < 16384)       { src = Wih0; local = idx;          base = 0;      IN = 32; }
    else if (idx < 81920)  { src = Whh0; local = idx - 16384;  base = 16384;  IN = 128; }
    else if (idx < 147456) { src = Wih1; local = idx - 81920;  base = 81920;  IN = 128; }
    else                   { src = Whh1; local = idx - 147456; base = 147456; IN = 128; }
    int pair = local >> 10, g = (local >> 1) & 511, lo = local & 1;
    int k = pair*2 + lo;
    w16[base + local] = f2bf(src[g*IN + k]);
  } else if (idx < 213504) {
    int g = idx - 212992; ws[WS_B0 + g] = bih0[g] + bhh0[g];
  } else if (idx < 214016) {
    int g = idx - 213504; ws[WS_B1 + g] = bih1[g] + bhh1[g];
  } else if (idx < 218112) {              // Q = QL QL^T + 1e-3 I
    int e = idx - 214016; int i = e >> 6, j = e & 63;
    float s = (i==j) ? 1e-3f : 0.f;
    for (int k = 0; k < 64; ++k) s += QL[i*64+k]*QL[j*64+k];
    ws[WS_Q + e] = s;
  } else if (idx < 219136) {              // R = RL RL^T + 1e-3 I
    int e = idx - 218112; int i = e >> 5, j = e & 31;
    float s = (i==j) ? 1e-3f : 0.f;
    for (int k = 0; k < 32; ++k) s += RL[i*32+k]*RL[j*32+k];
    ws[WS_R + e] = s;
  }
}

// ============ 2-layer LSTM + softmax head -> w[T][B][16] ============
// (unchanged from r9 — coalesced bf16 [k][512] reads, 4 barriers/step)
__global__ __launch_bounds__(512) void lstm_kernel(
    const float* __restrict__ as_, const float* __restrict__ ws,
    const float* __restrict__ linW, const float* __restrict__ linb,
    float* __restrict__ wout)
{
  const int b = blockIdx.x, tid = threadIdx.x;
  const unsigned* W0ih = (const unsigned*)ws;        // [16][512] pairs
  const unsigned* W0hh = W0ih + 16*512;              // [64][512]
  const unsigned* W1ih = W0hh + 64*512;              // [64][512]
  const unsigned* W1hh = W1ih + 64*512;              // [64][512]

  __shared__ float xs[2][32];
  __shared__ float h0[128];
  __shared__ float h1[128];
  __shared__ float gbuf[512];
  __shared__ float lw[16*132];                        // linW, pad-132 rows

  for (int e = tid; e < 2048; e += 512) lw[(e >> 7)*132 + (e & 127)] = linW[e];
  if (tid < 128) { h0[tid] = 0.f; h1[tid] = 0.f; }
  if (tid < 32)  xs[0][tid] = as_[(0*B_SZ + b)*AD + tid];
  float c0 = 0.f, c1 = 0.f;
  const float bias0 = ws[WS_B0 + tid];
  const float bias1 = ws[WS_B1 + tid];
  const float lbk = linb[tid & 15];
  __syncthreads();

  for (int t = 0; t < T_LEN; ++t) {
    const int cp = t & 1, np = cp ^ 1;
    { // gates layer 0
      float acc = bias0;
      #pragma unroll 4
      for (int kk = 0; kk < 16; ++kk) {
        const unsigned u = W0ih[kk*512 + tid];
        acc += __uint_as_float(u << 16) * xs[cp][2*kk]
             + __uint_as_float(u & 0xFFFF0000u) * xs[cp][2*kk+1];
      }
      #pragma unroll 8
      for (int kk = 0; kk < 64; ++kk) {
        const unsigned u = W0hh[kk*512 + tid];
        acc += __uint_as_float(u << 16) * h0[2*kk]
             + __uint_as_float(u & 0xFFFF0000u) * h0[2*kk+1];
      }
      gbuf[tid] = acc;
    }
    __syncthreads();                                  // B1
    if (tid < 128) {
      float ig = sigmoidf_(gbuf[tid]);
      float fg = sigmoidf_(gbuf[tid+128]);
      float gg = tanhf(gbuf[tid+256]);
      float og = sigmoidf_(gbuf[tid+384]);
      c0 = fg*c0 + ig*gg;
      h0[tid] = og * tanhf(c0);
    } else if (tid < 160 && t+1 < T_LEN) {
      xs[np][tid-128] = as_[((t+1)*B_SZ + b)*AD + (tid-128)];
    }
    __syncthreads();                                  // B2
    { // gates layer 1
      float acc = bias1;
      #pragma unroll 8
      for (int kk = 0; kk < 64; ++kk) {
        const unsigned u = W1ih[kk*512 + tid];
        acc += __uint_as_float(u << 16) * h0[2*kk]
             + __uint_as_float(u & 0xFFFF0000u) * h0[2*kk+1];
      }
      #pragma unroll 8
      for (int kk = 0; kk < 64; ++kk) {
        const unsigned u = W1hh[kk*512 + tid];
        acc += __uint_as_float(u << 16) * h1[2*kk]
             + __uint_as_float(u & 0xFFFF0000u) * h1[2*kk+1];
      }
      gbuf[tid] = acc;
    }
    __syncthreads();                                  // B3
    if (tid < 128) {
      float ig = sigmoidf_(gbuf[tid]);
      float fg = sigmoidf_(gbuf[tid+128]);
      float gg = tanhf(gbuf[tid+256]);
      float og = sigmoidf_(gbuf[tid+384]);
      c1 = fg*c1 + ig*gg;
      h1[tid] = og * tanhf(c1);
    }
    __syncthreads();                                  // B4
    if (tid < 64) {
      const int k = tid & 15, q = tid >> 4;
      float acc = 0.f;
      const float* lr = &lw[k*132 + q*32];
      const float* hr = &h1[q*32];
      #pragma unroll 8
      for (int j = 0; j < 32; ++j) acc += lr[j] * hr[j];
      acc += __shfl_xor(acc, 16);
      acc += __shfl_xor(acc, 32);
      const float logit = acc + lbk;
      float m = logit;
      m = fmaxf(m, __shfl_xor(m, 1));
      m = fmaxf(m, __shfl_xor(m, 2));
      m = fmaxf(m, __shfl_xor(m, 4));
      m = fmaxf(m, __shfl_xor(m, 8));
      const float e = expf(logit - m);
      float s = e;
      s += __shfl_xor(s, 1); s += __shfl_xor(s, 2);
      s += __shfl_xor(s, 4); s += __shfl_xor(s, 8);
      if (tid < 16) wout[(t*B_SZ + b)*KMIX + k] = e / s;
    }
  }
}

// ============ mix (unchanged) ============
__global__ __launch_bounds__(256) void mix_kernel(
    const float* __restrict__ w, const float* __restrict__ AK,
    const float* __restrict__ CK, float* __restrict__ out)
{
  float* matA = out + OUT_MATA;
  float* matC = out + OUT_MATC;
  const int tb0 = blockIdx.x * 16;
  const int tid = threadIdx.x;
  __shared__ float wl[16][16];
  { int lt = tid >> 4, k = tid & 15; wl[lt][k] = w[(tb0 + lt)*16 + k]; }
  __syncthreads();

  for (int e = tid; e < ZD*ZD; e += 256) {
    float v[16];
    #pragma unroll
    for (int u = 0; u < 16; ++u) v[u] = 0.f;
    #pragma unroll 4
    for (int k = 0; k < 16; ++k) {
      float a = AK[k*ZD*ZD + e];
      #pragma unroll
      for (int u = 0; u < 16; ++u) v[u] += wl[u][k] * a;
    }
    #pragma unroll
    for (int u = 0; u < 16; ++u) matA[(size_t)(tb0+u)*(ZD*ZD) + e] = v[u];
  }
  for (int e = tid; e < AD*ZD; e += 256) {
    float v[16];
    #pragma unroll
    for (int u = 0; u < 16; ++u) v[u] = 0.f;
    #pragma unroll 4
    for (int k = 0; k < 16; ++k) {
      float a = CK[k*AD*ZD + e];
      #pragma unroll
      for (int u = 0; u < 16; ++u) v[u] += wl[u][k] * a;
    }
    #pragma unroll
    for (int u = 0; u < 16; ++u) matC[(size_t)(tb0+u)*(AD*ZD) + e] = v[u];
  }
}

// U slot: U[i][q*4..q*4+3] = sum_k A[i][k] * covp[k][q*4..]
__device__ __forceinline__ void u_slot(const float* __restrict__ Atc,
                                       const float* __restrict__ cov,
                                       float* __restrict__ Um, int ii, int qq)
{
  const int c0 = qq*4;
  float4 acc = make_float4(0,0,0,0);
  #pragma unroll 8
  for (int k = 0; k < 64; ++k) {
    const float a = Atc[k*68 + ii];
    const float4 b4 = *(const float4*)&cov[k*68 + c0];
    acc.x += a*b4.x; acc.y += a*b4.y; acc.z += a*b4.z; acc.w += a*b4.w;
  }
  *(float4*)&Um[ii*68 + c0] = acc;
}

// ============ Kalman filter: one block (512 thr, 8 waves) per batch ============
// Restructured dataflow (r10): covnext = (A covp)A^T - (A W^T)(A W^T)^T + Q.
// U = A@covp_aug is innovation-independent -> computed by waves 1-7 WHILE
// wave 0 runs the serial Cholesky (hides the ~2us chain). V^T = W@(A cols)
// overlaps the covt output pass. 6 barriers/step (was 7), covt never stored
// to LDS. Register discipline per r3-r7 (no co-live arrays, no runtime
// array indexing, no cross-phase prefetch regs).
__global__ __launch_bounds__(512, 1) void kalman_kernel(
    const float* __restrict__ as_, const float* __restrict__ ws,
    float* __restrict__ out)
{
  const int b = blockIdx.x, tid = threadIdx.x;
  const float* Rm = ws + WS_R;
  const float* Qg = ws + WS_Q;
  const float* matA = out + OUT_MATA;
  const float* matC = out + OUT_MATC;
  float* means  = out + OUT_MEANS;
  float* covs   = out + OUT_COVS;
  float* nmeans = out + OUT_NMEANS;
  float* ncovs  = out + OUT_NCOVS;

  __shared__ __align__(16) float covp[64*68];   // aug: col 64 = meanp; 65-67 = 0
  __shared__ __align__(16) float At[2][64*68];  // A^T, double-buffered
  __shared__ __align__(16) float Cm[2][32*68];  // C rows, stride 68
  __shared__ __align__(16) float CPm[32*68];    // [CP | Cmeanp - a]
  __shared__ __align__(16) float Wm[32*68];     // L^{-1} CPaug
  __shared__ float Smat[32*36];                 // S -> L (inv diag on diagonal)
  __shared__ __align__(16) float Um[64*68];     // A @ covp_aug
  __shared__ __align__(16) float Vt[32*68];     // V^T: Vt[a][i] = (A W^T)[i][a]
  __shared__ __align__(16) float Ql[64*68];     // Q staged

  // ---- init
  for (int e = tid; e < 64*68; e += 512) covp[e] = 0.f;   // incl cols 64-67
  __syncthreads();
  for (int e = tid; e < 64*64; e += 512) {
    const int i = e >> 6, j = e & 63;
    Ql[i*68 + j]   = Qg[e];
    covp[i*68 + j] = (i == j) ? 1.f : 0.f;
  }
  {
    const float* Ag = matA + (size_t)b*4096;
    const float* Cg = matC + (size_t)b*2048;
    for (int e = tid; e < 4096; e += 512) At[0][(e & 63)*68 + (e >> 6)] = Ag[e];
    for (int e = tid; e < 2048; e += 512) Cm[0][(e >> 6)*68 + (e & 63)] = Cg[e];
  }
  __syncthreads();

  int cur = 0;
  for (int t = 0; t < T_LEN; ++t) {
    const int tb = t*B_SZ + b;
    const int nxt = cur ^ 1;
    float areg = 0.f;
    if ((tid & 15) == 15) areg = as_[(size_t)tb*AD + (tid >> 4)];

    // ---- PH1: CPaug = C @ covp_aug   (32 rows x 65)
    {
      const int i = tid >> 4, j0 = (tid & 15)*4;
      const bool do64 = ((tid & 15) == 15);
      const float* Crow = &Cm[cur][i*68];
      float4 acc = make_float4(0,0,0,0); float s64 = 0.f;
      #pragma unroll 4
      for (int k4 = 0; k4 < 16; ++k4) {
        const float4 a4 = *(const float4*)&Crow[k4*4];
        const float4 b0 = *(const float4*)&covp[(k4*4+0)*68 + j0];
        const float4 b1 = *(const float4*)&covp[(k4*4+1)*68 + j0];
        const float4 b2 = *(const float4*)&covp[(k4*4+2)*68 + j0];
        const float4 b3 = *(const float4*)&covp[(k4*4+3)*68 + j0];
        acc.x += a4.x*b0.x + a4.y*b1.x + a4.z*b2.x + a4.w*b3.x;
        acc.y += a4.x*b0.y + a4.y*b1.y + a4.z*b2.y + a4.w*b3.y;
        acc.z += a4.x*b0.z + a4.y*b1.z + a4.z*b2.z + a4.w*b3.z;
        acc.w += a4.x*b0.w + a4.y*b1.w + a4.z*b2.w + a4.w*b3.w;
        if (do64) {
          s64 += a4.x*covp[(k4*4+0)*68+64] + a4.y*covp[(k4*4+1)*68+64]
               + a4.z*covp[(k4*4+2)*68+64] + a4.w*covp[(k4*4+3)*68+64];
        }
      }
      *(float4*)&CPm[i*68 + j0] = acc;
      if (do64) CPm[i*68 + 64] = s64 - areg;   // C meanp - a
    }
    __syncthreads();
    // ---- PH2: S = CP @ C^T + R
    {
      const int i = tid >> 4, j0 = (tid & 15)*2;
      const float* CProw = &CPm[i*68];
      const float* Cr0 = &Cm[cur][(j0+0)*68];
      const float* Cr1 = &Cm[cur][(j0+1)*68];
      float a0 = 0.f, a1 = 0.f;
      #pragma unroll 4
      for (int k4 = 0; k4 < 16; ++k4) {
        const float4 cp4 = *(const float4*)&CProw[k4*4];
        const float4 c04 = *(const float4*)&Cr0[k4*4];
        const float4 c14 = *(const float4*)&Cr1[k4*4];
        a0 += cp4.x*c04.x + cp4.y*c04.y + cp4.z*c04.z + cp4.w*c04.w;
        a1 += cp4.x*c14.x + cp4.y*c14.y + cp4.z*c14.z + cp4.w*c14.w;
      }
      Smat[i*36 + j0+0] = a0 + Rm[i*32 + j0+0];
      Smat[i*36 + j0+1] = a1 + Rm[i*32 + j0+1];
    }
    __syncthreads();
    // ---- PH3: wave 0 Cholesky  ||  waves 1-7: U = A @ covp_aug (17x64 slots)
    {
      const int wv = tid >> 6, lane = tid & 63;
      if (wv == 0) {
        if (lane < 32) {
          float Lr[32];
          float invd = 0.f;   // static select only (runtime Lr[lane] = r3 bug)
          #pragma unroll
          for (int j = 0; j < 32; ++j) Lr[j] = Smat[lane*36 + j];
          #pragma unroll
          for (int k = 0; k < 32; ++k) {
            const float piv = __shfl(Lr[k], k);
            const float ir  = 1.0f / sqrtf(piv);
            const float lik = Lr[k] * ir;
            invd = (lane == k) ? ir : invd;
            #pragma unroll
            for (int j = k+1; j < 32; ++j) {
              const float ljk = __shfl(lik, j);   // all 32 source lanes active
              Lr[j] -= lik * ljk;
            }
            Lr[k] = lik;
          }
          #pragma unroll
          for (int j = 0; j < 32; ++j)
            if (j < lane) Smat[lane*36 + j] = Lr[j];
          Smat[lane*36 + lane] = invd;
        }
      } else {
        const int su2 = tid - 64;                 // 0..447
        const float* Atc = At[cur];
        { const int s = su2;       u_slot(Atc, covp, Um, s & 63, s >> 6); }
        { const int s = su2 + 448; u_slot(Atc, covp, Um, s & 63, s >> 6); }
        if (su2 < 192) { const int s = su2 + 896; u_slot(Atc, covp, Um, s & 63, s >> 6); }
      }
    }
    __syncthreads();
    // ---- PH4: threads 0-64 forward solve W = L^{-1} CPaug  ||  128+ stage t+1
    {
      if (tid < 65) {
        const int c = tid;
        float s[32];
        #pragma unroll
        for (int i = 0; i < 32; ++i) s[i] = CPm[i*68 + c];
        #pragma unroll
        for (int k = 0; k < 32; ++k) {
          const float y = s[k] * Smat[k*36 + k];     // diag holds 1/L[k][k]
          Wm[k*68 + c] = y;
          #pragma unroll
          for (int i = k+1; i < 32; ++i)
            s[i] -= Smat[i*36 + k] * y;
        }
      } else if (tid >= 128 && t < T_LEN-1) {
        const int su = tid - 128;                 // 0..383
        const float* Ag = matA + (size_t)(tb+64)*4096;
        const float* Cg = matC + (size_t)(tb+64)*2048;
        const float4 q0 = *(const float4*)&Ag[su*4];
        const float4 q1 = *(const float4*)&Ag[(su+384)*4];
        const float4 q2 = (su < 256) ? *(const float4*)&Ag[(su+768)*4]
                                     : *(const float4*)&Cg[(su-256)*4];
        const float4 q3 = *(const float4*)&Cg[(su+128)*4];
        { const int c = su;       const int i = c>>4, j = (c&15)*4;
          At[nxt][(j+0)*68+i]=q0.x; At[nxt][(j+1)*68+i]=q0.y; At[nxt][(j+2)*68+i]=q0.z; At[nxt][(j+3)*68+i]=q0.w; }
        { const int c = su + 384; const int i = c>>4, j = (c&15)*4;
          At[nxt][(j+0)*68+i]=q1.x; At[nxt][(j+1)*68+i]=q1.y; At[nxt][(j+2)*68+i]=q1.z; At[nxt][(j+3)*68+i]=q1.w; }
        if (su < 256) { const int c = su + 768; const int i = c>>4, j = (c&15)*4;
          At[nxt][(j+0)*68+i]=q2.x; At[nxt][(j+1)*68+i]=q2.y; At[nxt][(j+2)*68+i]=q2.z; At[nxt][(j+3)*68+i]=q2.w; }
        else { const int cc = su - 256; *(float4*)&Cm[nxt][(cc>>4)*68 + (cc&15)*4] = q2; }
        { const int cc = su + 128;      *(float4*)&Cm[nxt][(cc>>4)*68 + (cc&15)*4] = q3; }
      }
    }
    __syncthreads();
    // ---- PH5: covt = covp - W^T W -> covs/means (global only, no LDS write)
    //           then Vt[a][i] = sum_k W[a][k] A[i][k]  (one 4-col slot/thread)
    {
      const int j = tid >> 3, c0 = (tid & 7)*8;
      const bool do64 = ((tid & 7) == 7);
      float4 a0 = make_float4(0,0,0,0), a1 = a0; float s64 = 0.f;
      #pragma unroll 8
      for (int k = 0; k < 32; ++k) {
        const float a = Wm[k*68 + j];
        const float4 b0 = *(const float4*)&Wm[k*68 + c0];
        const float4 b1 = *(const float4*)&Wm[k*68 + c0 + 4];
        a0.x += a*b0.x; a0.y += a*b0.y; a0.z += a*b0.z; a0.w += a*b0.w;
        a1.x += a*b1.x; a1.y += a*b1.y; a1.z += a*b1.z; a1.w += a*b1.w;
        if (do64) s64 += a * Wm[k*68 + 64];
      }
      float4 c4a = *(const float4*)&covp[j*68 + c0];
      float4 c4b = *(const float4*)&covp[j*68 + c0 + 4];
      c4a.x -= a0.x; c4a.y -= a0.y; c4a.z -= a0.z; c4a.w -= a0.w;
      c4b.x -= a1.x; c4b.y -= a1.y; c4b.z -= a1.z; c4b.w -= a1.w;
      *(float4*)&covs[(size_t)tb*4096 + j*64 + c0]     = c4a;
      *(float4*)&covs[(size_t)tb*4096 + j*64 + c0 + 4] = c4b;
      if (do64) means[(size_t)tb*64 + j] = covp[j*68 + 64] - s64;
    }
    {
      const int a = tid & 31, c0 = (tid >> 5)*4;   // 32 rows x 16 quads = 512
      const float* Wr  = &Wm[a*68];
      const float* Atc = At[cur];
      float4 acc = make_float4(0,0,0,0);
      #pragma unroll 4
      for (int k4 = 0; k4 < 16; ++k4) {
        const float4 w4 = *(const float4*)&Wr[k4*4];
        const float4 b0 = *(const float4*)&Atc[(k4*4+0)*68 + c0];
        const float4 b1 = *(const float4*)&Atc[(k4*4+1)*68 + c0];
        const float4 b2 = *(const float4*)&Atc[(k4*4+2)*68 + c0];
        const float4 b3 = *(const float4*)&Atc[(k4*4+3)*68 + c0];
        acc.x += w4.x*b0.x + w4.y*b1.x + w4.z*b2.x + w4.w*b3.x;
        acc.y += w4.x*b0.y + w4.y*b1.y + w4.z*b2.y + w4.w*b3.y;
        acc.z += w4.x*b0.z + w4.y*b1.z + w4.z*b2.z + w4.w*b3.z;
        acc.w += w4.x*b0.w + w4.y*b1.w + w4.z*b2.w + w4.w*b3.w;
      }
      *(float4*)&Vt[a*68 + c0] = acc;
    }
    __syncthreads();
    // ---- PH6: covnext = U A^T - V V^T + Q -> covp; ncovs/nmeans; col64
    {
      const int i = tid >> 3, j0 = (tid & 7)*8;
      const float* Atc  = At[cur];
      const float* trow = &Um[i*68];
      float4 a0 = *(const float4*)&Ql[i*68 + j0];
      float4 a1 = *(const float4*)&Ql[i*68 + j0 + 4];
      #pragma unroll 4
      for (int k4 = 0; k4 < 16; ++k4) {
        const float4 t4 = *(const float4*)&trow[k4*4];
        #pragma unroll
        for (int m = 0; m < 4; ++m) {
          const float a = (m==0)?t4.x:(m==1)?t4.y:(m==2)?t4.z:t4.w;
          const float4 b0 = *(const float4*)&Atc[(k4*4+m)*68 + j0];
          const float4 b1 = *(const float4*)&Atc[(k4*4+m)*68 + j0 + 4];
          a0.x += a*b0.x; a0.y += a*b0.y; a0.z += a*b0.z; a0.w += a*b0.w;
          a1.x += a*b1.x; a1.y += a*b1.y; a1.z += a*b1.z; a1.w += a*b1.w;
        }
      }
      #pragma unroll 8
      for (int a = 0; a < 32; ++a) {
        const float va = Vt[a*68 + i];
        const float4 b0 = *(const float4*)&Vt[a*68 + j0];
        const float4 b1 = *(const float4*)&Vt[a*68 + j0 + 4];
        a0.x -= va*b0.x; a0.y -= va*b0.y; a0.z -= va*b0.z; a0.w -= va*b0.w;
        a1.x -= va*b1.x; a1.y -= va*b1.y; a1.z -= va*b1.z; a1.w -= va*b1.w;
      }
      *(float4*)&covp[i*68 + j0]     = a0;
      *(float4*)&covp[i*68 + j0 + 4] = a1;
      *(float4*)&ncovs[(size_t)tb*4096 + i*64 + j0]     = a0;
      *(float4*)&ncovs[(size_t)tb*4096 + i*64 + j0 + 4] = a1;
      if ((tid & 7) == 7) {
        float s64 = Um[i*68 + 64];                 // A @ meanp
        #pragma unroll 8
        for (int a = 0; a < 32; ++a) s64 -= Vt[a*68 + i] * Wm[a*68 + 64];
        covp[i*68 + 64] = s64;                     // mean_next
        nmeans[(size_t)tb*64 + i] = s64;
      }
    }
    __syncthreads();
    cur = nxt;
  }
}

extern "C" void kernel_launch(void* const* d_in, const int* in_sizes, int n_in,
                              void* d_out, int out_size, void* d_ws, size_t ws_size,
                              hipStream_t stream) {
  const float* as_  = (const float*)d_in[0];
  const float* AK   = (const float*)d_in[1];
  const float* CK   = (const float*)d_in[2];
  const float* QL   = (const float*)d_in[3];
  const float* RL   = (const float*)d_in[4];
  const float* linW = (const float*)d_in[5];
  const float* linb = (const float*)d_in[6];
  const float* Wih0 = (const float*)d_in[7];
  const float* Whh0 = (const float*)d_in[8];
  const float* bih0 = (const float*)d_in[9];
  const float* bhh0 = (const float*)d_in[10];
  const float* Wih1 = (const float*)d_in[11];
  const float* Whh1 = (const float*)d_in[12];
  const float* bih1 = (const float*)d_in[13];
  const float* bhh1 = (const float*)d_in[14];
  float* out = (float*)d_out;
  float* ws  = (float*)d_ws;

  prep_kernel<<<856, 256, 0, stream>>>(Wih0, Whh0, bih0, bhh0,
                                       Wih1, Whh1, bih1, bhh1, QL, RL, ws);
  lstm_kernel<<<B_SZ, 512, 0, stream>>>(as_, ws, linW, linb, ws + WS_W);
  mix_kernel<<<(T_LEN*B_SZ)/16, 256, 0, stream>>>(ws + WS_W, AK, CK, out);
  kalman_kernel<<<B_SZ, 512, 0, stream>>>(as_, ws, out);
}